// Round 7
// baseline (219.013 us; speedup 1.0000x reference)
//
#include <hip/hip_runtime.h>

#define BB 8
#define NN 8192
#define NPOINT 2048
#define NSAMPLE 64
#define CIN 64
#define RADIUS 0.2f
#define R2 (RADIUS * RADIUS)

// d_out layout (flat floats, reference return order)
#define OFF_NEWXYZ 0
#define OFF_FEAT (BB * NPOINT * 3)
#define OFF_INDS (OFF_FEAT + BB * NPOINT * 128)
#define OFF_IDX (OFF_INDS + BB * NPOINT)

typedef _Float16 half8 __attribute__((ext_vector_type(8)));
typedef _Float16 half4 __attribute__((ext_vector_type(4)));
typedef float floatx16 __attribute__((ext_vector_type(16)));

// Per-wave LDS slice (halves). P0=88 (K0=80 + pad), P1=72. Row starts stay
// 16B-aligned for b128 fragment reads.
#define P0 88
#define P1 72
#define X_LOC 0
#define H_LOC (64 * P0)                 // 5632
#define XH_WAVE (64 * P0 + 64 * P1)     // 10240 halves = 20480 B per wave
// Weight staging regions (block-shared, overlap the wave slices, used once
// before any X/H writes):
#define WT0_S 0
#define WT1_S (64 * P0)
#define WT2_S (64 * P0 + 64 * P1)       // 10240..19456 (fits in 20480*2)

#define QPW 8  // queries per wave; grid 1024 blocks = 4 blocks/CU, no tail

// ---------------------------------------------------------------------------
// Kernel 1: new_xyz gather + inds passthrough + ball query.
// Wave per query, 4 candidates per lane per iteration (k-major order keeps
// exact first-NSAMPLE-in-point-order semantics via 4 sequential ballots).
// NOTE: distance formula must stay qq + nn - 2*dot to match reference
// rounding — borderline hit flips would corrupt the idx output.
// ---------------------------------------------------------------------------
__global__ __launch_bounds__(256) void ballq_kernel(
    const float* __restrict__ xyz, const int* __restrict__ inds,
    float* __restrict__ out) {
  const int wq = (blockIdx.x * 256 + threadIdx.x) >> 6;  // query id
  const int lane = threadIdx.x & 63;
  const int b = wq >> 11;  // NPOINT = 2048

  const float* xb = xyz + (size_t)b * NN * 3;
  const int ind = inds[wq];
  const float cx = xb[ind * 3 + 0];
  const float cy = xb[ind * 3 + 1];
  const float cz = xb[ind * 3 + 2];

  if (lane == 0) {
    out[OFF_NEWXYZ + (size_t)wq * 3 + 0] = cx;
    out[OFF_NEWXYZ + (size_t)wq * 3 + 1] = cy;
    out[OFF_NEWXYZ + (size_t)wq * 3 + 2] = cz;
    out[OFF_INDS + wq] = (float)ind;
  }

  const float qq = cx * cx + cy * cy + cz * cz;
  float* myidx = out + OFF_IDX + (size_t)wq * NSAMPLE;

  int cnt = 0;
  for (int j0 = 0; j0 < NN; j0 += 256) {
    float px[4], py[4], pz[4];
#pragma unroll
    for (int k = 0; k < 4; ++k) {  // 12 independent loads up front
      const float* p = xb + (size_t)(j0 + k * 64 + lane) * 3;
      px[k] = p[0];
      py[k] = p[1];
      pz[k] = p[2];
    }
#pragma unroll
    for (int k = 0; k < 4; ++k) {
      const float nn = px[k] * px[k] + py[k] * py[k] + pz[k] * pz[k];
      const float dot = cx * px[k] + cy * py[k] + cz * pz[k];
      const bool hit = (qq + nn - 2.0f * dot) < R2;
      const unsigned long long m = __ballot(hit);
      if (hit) {
        const int pos = cnt + (int)__popcll(m & ((1ull << lane) - 1ull));
        if (pos < NSAMPLE) myidx[pos] = (float)(j0 + k * 64 + lane);
      }
      cnt += (int)__popcll(m);
    }
    if (cnt >= NSAMPLE) break;
  }
  // Pad: center point always hits itself -> cnt >= 1 -> myidx[0] valid.
  const float f0 = myidx[0];
  if (lane >= cnt) myidx[lane] = f0;
}

// ---------------------------------------------------------------------------
// Kernel 2: barrier-free MFMA MLP. 128-thread block = 2 independent waves;
// each wave owns one query at a time in a private LDS slice.
// L0/L1: A = weight fragments (registers/AGPRs), B = activation fragments
// (LDS b128). C/D: lane owns a SAMPLE column, output channels come in
// reg-groups of 4 consecutive rows -> H written as half4 ds_write_b64
// (4 per tile) instead of 16 scalar u16 writes. t1 is row-indexed now ->
// read from a 256B LDS table as float4 per write group.
// L2: A = H1 activations, B = weight fragments -> lane owns a d2 column,
// rows = samples -> maxpool is a register reduction + 1 shuffle.
// ---------------------------------------------------------------------------
__global__ __launch_bounds__(128, 2) void mlp_mfma(
    const float* __restrict__ xyz, const float* __restrict__ features,
    const int* __restrict__ inds,
    const float* __restrict__ w0, const float* __restrict__ s0,
    const float* __restrict__ t0, const float* __restrict__ w1,
    const float* __restrict__ s1, const float* __restrict__ t1,
    const float* __restrict__ w2, const float* __restrict__ s2,
    const float* __restrict__ t2, float* __restrict__ out) {
  __shared__ _Float16 sm[2 * XH_WAVE];  // 40960 B
  __shared__ float t1sm[64];            // +256 B persistent t1 table
  const int tid = threadIdx.x;
  const int w = tid >> 6;
  const int l = tid & 63;
  const int l31 = l & 31;
  const int h5 = l >> 5;
  const int koff = h5 * 8;  // fragment k-offset in halves

  // ---- stage folded weights into fragment-layout LDS (block-wide, once) ----
  {
    const int d = tid >> 1, hf = tid & 1;
    const float sd0 = s0[d], td0 = t0[d], sd1 = s1[d];
#pragma unroll
    for (int j = 0; j < 44; ++j) {
      const int c = hf * 44 + j;
      float v = 0.0f;
      if (c < 64) v = w0[(3 + c) * 64 + d] * sd0;        // feature channels
      else if (c < 67) v = w0[(c - 64) * 64 + d] * sd0;  // xyz channels
      else if (c == 67) v = td0;                         // bias channel
      sm[WT0_S + d * P0 + c] = (_Float16)v;
    }
#pragma unroll
    for (int j = 0; j < 32; ++j) {
      const int c = hf * 32 + j;
      sm[WT1_S + d * P1 + c] = (_Float16)(w1[c * 64 + d] * sd1);
    }
    const int ch = tid;  // 0..127
    const float sch = s2[ch];
#pragma unroll
    for (int c = 0; c < 64; ++c)
      sm[WT2_S + ch * P1 + c] = (_Float16)(w2[c * 128 + ch] * sch);
    if (tid < 64) t1sm[tid] = t1[tid];
  }
  __syncthreads();

  // ---- hoist weight fragments + t vectors into registers ----
  // a0f/a1f: A-operand fragments of W0'^T / W1'^T (lane = output-channel row)
  // b2f: B-operand fragments of W2' (lane = d2 column)
  half8 a0f[2][5], a1f[2][4], b2f[4][4];
#pragma unroll
  for (int mt = 0; mt < 2; ++mt)
#pragma unroll
    for (int ks = 0; ks < 5; ++ks)
      a0f[mt][ks] =
          *(const half8*)&sm[WT0_S + (mt * 32 + l31) * P0 + ks * 16 + koff];
#pragma unroll
  for (int mt = 0; mt < 2; ++mt)
#pragma unroll
    for (int ks = 0; ks < 4; ++ks)
      a1f[mt][ks] =
          *(const half8*)&sm[WT1_S + (mt * 32 + l31) * P1 + ks * 16 + koff];
#pragma unroll
  for (int ct = 0; ct < 4; ++ct)
#pragma unroll
    for (int ks = 0; ks < 4; ++ks)
      b2f[ct][ks] =
          *(const half8*)&sm[WT2_S + (ct * 32 + l31) * P1 + ks * 16 + koff];
  float t2v[4];
#pragma unroll
  for (int ct = 0; ct < 4; ++ct) t2v[ct] = t2[ct * 32 + l31];
  __syncthreads();  // all fragment reads done before X/H overwrite the region

  _Float16* xbuf = sm + w * XH_WAVE + X_LOC;
  _Float16* hbuf = sm + w * XH_WAVE + H_LOC;
  // zero X K-pad halves 72..79 once (64..71 rewritten per query)
  {
    half8 z = {};
    *(half8*)&xbuf[l * P0 + 72] = z;
  }

  const int wq0 = (blockIdx.x * 2 + w) * QPW;
#pragma unroll 1
  for (int qi = 0; qi < QPW; ++qi) {
    const int q = wq0 + qi;
    const int b = q >> 11;

    // ---- gather + stage X (lane = sample) ----
    const int idxs = (int)out[OFF_IDX + (size_t)q * NSAMPLE + l];
    const float* xb = xyz + (size_t)b * NN * 3;
    const int ind = inds[q];
    const float cx = xb[ind * 3 + 0], cy = xb[ind * 3 + 1],
                cz = xb[ind * 3 + 2];
    const float ppx = xb[idxs * 3 + 0], ppy = xb[idxs * 3 + 1],
                ppz = xb[idxs * 3 + 2];
    const float4* fr =
        (const float4*)(features + ((size_t)b * NN + (size_t)idxs) * CIN);
    float4 f[16];
#pragma unroll
    for (int u = 0; u < 16; ++u) f[u] = fr[u];
#pragma unroll
    for (int u = 0; u < 8; ++u) {
      half8 hv;
      hv[0] = (_Float16)f[2 * u].x;
      hv[1] = (_Float16)f[2 * u].y;
      hv[2] = (_Float16)f[2 * u].z;
      hv[3] = (_Float16)f[2 * u].w;
      hv[4] = (_Float16)f[2 * u + 1].x;
      hv[5] = (_Float16)f[2 * u + 1].y;
      hv[6] = (_Float16)f[2 * u + 1].z;
      hv[7] = (_Float16)f[2 * u + 1].w;
      *(half8*)&xbuf[l * P0 + u * 8] = hv;
    }
    {
      half8 xv = {};
      xv[0] = (_Float16)((ppx - cx) * 5.0f);
      xv[1] = (_Float16)((ppy - cy) * 5.0f);
      xv[2] = (_Float16)((ppz - cz) * 5.0f);
      xv[3] = (_Float16)1.0f;  // bias channel 67
      *(half8*)&xbuf[l * P0 + 64] = xv;
    }

    // ---- L0: C = W0'^T x X-tiles -> H0[sample][d0], b64 writes ----
    {
      half8 xa[2][5];  // B-operand fragments (lane = sample column)
#pragma unroll
      for (int nt = 0; nt < 2; ++nt)
#pragma unroll
        for (int ks = 0; ks < 5; ++ks)
          xa[nt][ks] =
              *(const half8*)&xbuf[(nt * 32 + l31) * P0 + ks * 16 + koff];
#pragma unroll
      for (int mt = 0; mt < 2; ++mt)
#pragma unroll
        for (int nt = 0; nt < 2; ++nt) {
          floatx16 acc;
#pragma unroll
          for (int i = 0; i < 16; ++i) acc[i] = 0.0f;
#pragma unroll
          for (int ks = 0; ks < 5; ++ks)
            acc = __builtin_amdgcn_mfma_f32_32x32x16_f16(a0f[mt][ks],
                                                         xa[nt][ks], acc,
                                                         0, 0, 0);
          // lane owns sample col nt*32+l31; rows (d0) in groups of 4
#pragma unroll
          for (int g = 0; g < 4; ++g) {
            half4 hv;
#pragma unroll
            for (int r = 0; r < 4; ++r)
              hv[r] = (_Float16)fmaxf(acc[4 * g + r], 0.0f);
            *(half4*)&hbuf[(nt * 32 + l31) * P1 + mt * 32 + 8 * g + 4 * h5] =
                hv;
          }
        }
    }

    // ---- L1: C = W1'^T x H0-tiles -> H1[sample][d1] into xbuf ----
    {
      half8 ha[2][4];
#pragma unroll
      for (int nt = 0; nt < 2; ++nt)
#pragma unroll
        for (int ks = 0; ks < 4; ++ks)
          ha[nt][ks] =
              *(const half8*)&hbuf[(nt * 32 + l31) * P1 + ks * 16 + koff];
#pragma unroll
      for (int mt = 0; mt < 2; ++mt)
#pragma unroll
        for (int nt = 0; nt < 2; ++nt) {
          floatx16 acc;
#pragma unroll
          for (int i = 0; i < 16; ++i) acc[i] = 0.0f;
#pragma unroll
          for (int ks = 0; ks < 4; ++ks)
            acc = __builtin_amdgcn_mfma_f32_32x32x16_f16(a1f[mt][ks],
                                                         ha[nt][ks], acc,
                                                         0, 0, 0);
#pragma unroll
          for (int g = 0; g < 4; ++g) {
            const float4 tq = *(const float4*)&t1sm[mt * 32 + 8 * g + 4 * h5];
            half4 hv;
            hv[0] = (_Float16)fmaxf(acc[4 * g + 0] + tq.x, 0.0f);
            hv[1] = (_Float16)fmaxf(acc[4 * g + 1] + tq.y, 0.0f);
            hv[2] = (_Float16)fmaxf(acc[4 * g + 2] + tq.z, 0.0f);
            hv[3] = (_Float16)fmaxf(acc[4 * g + 3] + tq.w, 0.0f);
            *(half4*)&xbuf[(nt * 32 + l31) * P0 + mt * 32 + 8 * g + 4 * h5] =
                hv;
          }
        }
    }

    // ---- L2: Y = H1 @ W2' (lane owns d2 column), fused maxpool ----
    {
      half8 h1a[2][4];
#pragma unroll
      for (int st = 0; st < 2; ++st)
#pragma unroll
        for (int ks = 0; ks < 4; ++ks)
          h1a[st][ks] =
              *(const half8*)&xbuf[(st * 32 + l31) * P0 + ks * 16 + koff];
#pragma unroll
      for (int ct = 0; ct < 4; ++ct) {
        floatx16 aA, aB;
#pragma unroll
        for (int i = 0; i < 16; ++i) {
          aA[i] = 0.0f;
          aB[i] = 0.0f;
        }
#pragma unroll
        for (int ks = 0; ks < 4; ++ks) {
          aA = __builtin_amdgcn_mfma_f32_32x32x16_f16(h1a[0][ks], b2f[ct][ks],
                                                      aA, 0, 0, 0);
          aB = __builtin_amdgcn_mfma_f32_32x32x16_f16(h1a[1][ks], b2f[ct][ks],
                                                      aB, 0, 0, 0);
        }
        float m = fmaxf(aA[0], aB[0]);
#pragma unroll
        for (int i = 1; i < 16; ++i) m = fmaxf(m, fmaxf(aA[i], aB[i]));
        float v = fmaxf(m + t2v[ct], 0.0f);  // relu(max+t) == max(relu(+t))
        v = fmaxf(v, __shfl_xor(v, 32, 64));  // merge complementary row halves
        if (l < 32) out[OFF_FEAT + (size_t)q * 128 + ct * 32 + l] = v;
      }
    }
  }
}

extern "C" void kernel_launch(void* const* d_in, const int* in_sizes, int n_in,
                              void* d_out, int out_size, void* d_ws,
                              size_t ws_size, hipStream_t stream) {
  const float* xyz = (const float*)d_in[0];
  const float* features = (const float*)d_in[1];
  const int* inds = (const int*)d_in[2];
  const float* w0 = (const float*)d_in[3];
  const float* s0 = (const float*)d_in[4];
  const float* t0 = (const float*)d_in[5];
  const float* w1 = (const float*)d_in[6];
  const float* s1 = (const float*)d_in[7];
  const float* t1 = (const float*)d_in[8];
  const float* w2 = (const float*)d_in[9];
  const float* s2 = (const float*)d_in[10];
  const float* t2 = (const float*)d_in[11];
  float* out = (float*)d_out;

  const int nquery = BB * NPOINT;  // 16384
  ballq_kernel<<<nquery / 4, 256, 0, stream>>>(xyz, inds, out);
  // 2 waves/block * QPW queries each -> 1024 blocks
  mlp_mfma<<<nquery / (2 * QPW), 128, 0, stream>>>(
      xyz, features, inds, w0, s0, t0, w1, s1, t1, w2, s2, t2, out);
}